// Round 15
// baseline (290.708 us; speedup 1.0000x reference)
//
#include <hip/hip_runtime.h>
#include <cmath>

#define EPSF 1e-5f

typedef __bf16 bfx8 __attribute__((ext_vector_type(8)));
typedef float  f32x4 __attribute__((ext_vector_type(4)));

__device__ __forceinline__ float4 ld4(const float* p){ return *(const float4*)p; }
__device__ __forceinline__ unsigned f2bf(float f){
    unsigned u = __builtin_bit_cast(unsigned, f);
    return (u + 0x7FFFu + ((u >> 16) & 1u)) >> 16;
}
__device__ __forceinline__ float bf2f(unsigned u){
    return __builtin_bit_cast(float, u << 16);
}
__device__ __forceinline__ bfx8 lds_ld(const char* p){ return *(const bfx8*)p; }
__device__ __forceinline__ unsigned short bf16u(float f){ return (unsigned short)f2bf(f); }

// ---------------------------------------------------------------------------
// weights -> bf16 FRAGMENT layout in global (B staging = pure linear copy):
//   seg<5 (128x128): chunk=(nf*4+ks)*64+ln, elem j = W[k][c],
//       c=nf*16+(ln&15), k=ks*32+(ln>>4)*8+j
//   seg5  (256x64):  chunk=(nf*8+ks)*64+ln, same with 64 cols.
// ---------------------------------------------------------------------------
__global__ __launch_bounds__(256)
void wconv_all(const float* __restrict__ s0, const float* __restrict__ s1,
               const float* __restrict__ s2, const float* __restrict__ s3,
               const float* __restrict__ s4, const float* __restrict__ s5,
               unsigned short* __restrict__ WT)
{
    int gid   = blockIdx.x*256 + threadIdx.x;
    int seg   = gid >> 11;
    int chunk = gid & 2047;
    int ln    = chunk & 63;
    unsigned short tmp[8];
    if (seg < 5) {
        const float* s = seg==0?s0: seg==1?s1: seg==2?s2: seg==3?s3: s4;
        int nf = chunk >> 8, ks = (chunk >> 6) & 3;
        int c  = nf*16 + (ln & 15);
        int k0 = ks*32 + (ln >> 4)*8;
        #pragma unroll
        for (int j = 0; j < 8; ++j) tmp[j] = bf16u(s[(size_t)(k0+j)*128 + c]);
        *(uint4*)&WT[seg*16384 + chunk*8] = *(uint4*)tmp;
    } else {
        int nf = chunk >> 9, ks = (chunk >> 6) & 7;
        int c  = nf*16 + (ln & 15);
        int k0 = ks*32 + (ln >> 4)*8;
        #pragma unroll
        for (int j = 0; j < 8; ++j) tmp[j] = bf16u(s5[(size_t)(k0+j)*64 + c]);
        *(uint4*)&WT[5*16384 + chunk*8] = *(uint4*)tmp;
    }
}

// ---------------------------------------------------------------------------
// PERSISTENT fused front end: grid=256 (1 block/CU, 128K LDS), grid-stride
// over 64-row tiles. All 3 weight matrices resident in LDS (staged once).
// Double-buffered x tile; next tile's x issued to regs BEFORE GEMM1 (T14),
// committed after GEMM3. 3 barriers/tile. Direct per-lane epilogue stores.
//   H = relu(LN(x@tfc+b)); G = relu(BN(x@gfc+b)) -> Gf,Gb
//   V = H@wv+b; XT = relu(LN(.5V+.5H)) -> XTb
//   [attention term ~1e-8, dropped: q,k normalized by GLOBAL Frobenius norm]
// ---------------------------------------------------------------------------
__global__ __launch_bounds__(256)
void fused_front(const float* __restrict__ x,
                 const unsigned short* __restrict__ wt_tfc,
                 const unsigned short* __restrict__ wt_wv,
                 const unsigned short* __restrict__ wt_gfc,
                 const float* __restrict__ tfcb, const float* __restrict__ ln0g,
                 const float* __restrict__ ln0b, const float* __restrict__ wvb,
                 const float* __restrict__ ln1g, const float* __restrict__ ln1b,
                 const float* __restrict__ gfcb, const float* __restrict__ bn0g,
                 const float* __restrict__ bn0b, const float* __restrict__ bn0m,
                 const float* __restrict__ bn0v,
                 unsigned short* __restrict__ XTb, float* __restrict__ Gf,
                 unsigned short* __restrict__ Gb, int nrows, int ntiles)
{
    __shared__ __align__(16) char lds[131072];
    char* ArA = lds;              // 16K x/H tile (XOR), buffer A
    char* ArB = lds + 16384;      // 16K buffer B
    char* Wt  = lds + 32768;      // 32K tfc frags (resident)
    char* Wg  = lds + 65536;      // 32K gfc frags (resident)
    char* Wv  = lds + 98304;      // 32K wv  frags (resident)
    const int tid = threadIdx.x;
    const int w = tid >> 6, ln = tid & 63, lr = ln & 15, lg = ln >> 4;
    const int ksw = (lr & 7) << 4;

    // --- stage all weights ONCE ---
    #pragma unroll
    for (int i = 0; i < 8; ++i) {
        int c = tid + i*256;
        *(uint4*)&Wt[c*16] = *(const uint4*)&wt_tfc[c*8];
        *(uint4*)&Wg[c*16] = *(const uint4*)&wt_gfc[c*8];
        *(uint4*)&Wv[c*16] = *(const uint4*)&wt_wv[c*8];
    }
    // --- stage x(first tile) into ArA ---
    {
        int t0 = blockIdx.x;
        #pragma unroll
        for (int i = 0; i < 4; ++i) {
            int c = tid + i*256, r = c >> 4, k0 = (c & 15)*8;
            int rr = t0*64 + r;
            uint4 v4 = make_uint4(0,0,0,0);
            if (t0 < ntiles && rr < nrows) {
                float4 f0 = ld4(&x[(size_t)rr*128 + k0]);
                float4 f1 = ld4(&x[(size_t)rr*128 + k0 + 4]);
                v4.x = f2bf(f0.x) | (f2bf(f0.y) << 16);
                v4.y = f2bf(f0.z) | (f2bf(f0.w) << 16);
                v4.z = f2bf(f1.x) | (f2bf(f1.y) << 16);
                v4.w = f2bf(f1.z) | (f2bf(f1.w) << 16);
            }
            *(uint4*)&ArA[r*256 + ((k0*2) ^ ((r&7)<<4))] = v4;
        }
    }
    __syncthreads();

    bool par = false;
    for (int tile = blockIdx.x; tile < ntiles; tile += gridDim.x) {
        char* Acur = par ? ArB : ArA;
        char* Anxt = par ? ArA : ArB;
        const int  row0 = tile*64;
        const int  nxt  = tile + gridDim.x;
        const bool havenxt = (nxt < ntiles);
        const char* Abase = &Acur[(w*16 + lr)*256];

        // --- T14: issue next tile's x loads early (hide under GEMMs) ---
        float4 xa[4], xb[4];
        if (havenxt) {
            #pragma unroll
            for (int i = 0; i < 4; ++i) {
                int c = tid + i*256, r = c >> 4, k0 = (c & 15)*8;
                int rr = nxt*64 + r;
                if (rr < nrows) {
                    xa[i] = ld4(&x[(size_t)rr*128 + k0]);
                    xb[i] = ld4(&x[(size_t)rr*128 + k0 + 4]);
                } else {
                    xa[i] = make_float4(0.f,0.f,0.f,0.f);
                    xb[i] = make_float4(0.f,0.f,0.f,0.f);
                }
            }
        }

        f32x4 acc[8];
        float h[8][4];

        // --- GEMM1: x @ tfc ; LN0+relu -> h ---
        #pragma unroll
        for (int nf = 0; nf < 8; ++nf) acc[nf] = (f32x4){0.f,0.f,0.f,0.f};
        #pragma unroll
        for (int ks = 0; ks < 4; ++ks) {
            int kb = ks*64 + lg*16;
            bfx8 a = lds_ld(Abase + (kb ^ ksw));
            #pragma unroll
            for (int nf = 0; nf < 8; ++nf) {
                bfx8 b = lds_ld(&Wt[(nf*4+ks)*1024 + ln*16]);
                acc[nf] = __builtin_amdgcn_mfma_f32_16x16x32_bf16(a, b, acc[nf], 0, 0, 0);
            }
        }
        {
            float gl[8], bl[8];
            #pragma unroll
            for (int nf = 0; nf < 8; ++nf) {
                int c = nf*16 + lr;
                gl[nf] = ln0g[c]; bl[nf] = ln0b[c];
                float bb = tfcb[c];
                #pragma unroll
                for (int i = 0; i < 4; ++i) h[nf][i] = acc[nf][i] + bb;
            }
            #pragma unroll
            for (int i = 0; i < 4; ++i) {
                float s = 0.f, s2 = 0.f;
                #pragma unroll
                for (int nf = 0; nf < 8; ++nf) { s += h[nf][i]; s2 += h[nf][i]*h[nf][i]; }
                #pragma unroll
                for (int m = 1; m < 16; m <<= 1) { s += __shfl_xor(s, m); s2 += __shfl_xor(s2, m); }
                float mean = s * (1.f/128.f);
                float inv  = rsqrtf(s2 * (1.f/128.f) - mean*mean + EPSF);
                #pragma unroll
                for (int nf = 0; nf < 8; ++nf)
                    h[nf][i] = fmaxf((h[nf][i]-mean)*inv*gl[nf] + bl[nf], 0.f);
            }
        }
        // --- GEMM3: x @ gfc ; BN+relu -> acc ; direct stores Gf/Gb ---
        #pragma unroll
        for (int nf = 0; nf < 8; ++nf) acc[nf] = (f32x4){0.f,0.f,0.f,0.f};
        #pragma unroll
        for (int ks = 0; ks < 4; ++ks) {
            int kb = ks*64 + lg*16;
            bfx8 a = lds_ld(Abase + (kb ^ ksw));
            #pragma unroll
            for (int nf = 0; nf < 8; ++nf) {
                bfx8 b = lds_ld(&Wg[(nf*4+ks)*1024 + ln*16]);
                acc[nf] = __builtin_amdgcn_mfma_f32_16x16x32_bf16(a, b, acc[nf], 0, 0, 0);
            }
        }
        #pragma unroll
        for (int nf = 0; nf < 8; ++nf) {
            int c = nf*16 + lr;
            float sc = bn0g[c] * rsqrtf(bn0v[c] + EPSF);
            float sh = bn0b[c] - bn0m[c]*sc;
            float bb = gfcb[c];
            #pragma unroll
            for (int i = 0; i < 4; ++i) {
                int r = row0 + w*16 + lg*4 + i;
                if (r < nrows) {
                    float v = fmaxf((acc[nf][i] + bb)*sc + sh, 0.f);
                    Gf[(size_t)r*128 + c] = v;
                    Gb[(size_t)r*128 + c] = bf16u(v);
                }
            }
        }
        // --- commit prefetched x -> Anxt ---
        if (havenxt) {
            #pragma unroll
            for (int i = 0; i < 4; ++i) {
                int c = tid + i*256, r = c >> 4, k0 = (c & 15)*8;
                uint4 v4;
                v4.x = f2bf(xa[i].x) | (f2bf(xa[i].y) << 16);
                v4.y = f2bf(xa[i].z) | (f2bf(xa[i].w) << 16);
                v4.z = f2bf(xb[i].x) | (f2bf(xb[i].y) << 16);
                v4.w = f2bf(xb[i].z) | (f2bf(xb[i].w) << 16);
                *(uint4*)&Anxt[r*256 + ((k0*2) ^ ((r&7)<<4))] = v4;
            }
        }
        __syncthreads();                              // (1) x-reads of Acur done
        // --- H -> Acur (XOR u16) ---
        #pragma unroll
        for (int nf = 0; nf < 8; ++nf) {
            int c = nf*16 + lr;
            #pragma unroll
            for (int i = 0; i < 4; ++i) {
                int r = w*16 + lg*4 + i;
                *(unsigned short*)&Acur[(r*256 + c*2) ^ ((r&7)<<4)] = bf16u(h[nf][i]);
            }
        }
        __syncthreads();                              // (2) H visible
        // --- GEMM2: H @ wv ; XT = relu(LN(.5V+.5H)) ; direct store XTb ---
        #pragma unroll
        for (int nf = 0; nf < 8; ++nf) acc[nf] = (f32x4){0.f,0.f,0.f,0.f};
        #pragma unroll
        for (int ks = 0; ks < 4; ++ks) {
            int kb = ks*64 + lg*16;
            bfx8 a = lds_ld(Abase + (kb ^ ksw));
            #pragma unroll
            for (int nf = 0; nf < 8; ++nf) {
                bfx8 b = lds_ld(&Wv[(nf*4+ks)*1024 + ln*16]);
                acc[nf] = __builtin_amdgcn_mfma_f32_16x16x32_bf16(a, b, acc[nf], 0, 0, 0);
            }
        }
        {
            float gl[8], bl[8];
            #pragma unroll
            for (int nf = 0; nf < 8; ++nf) {
                int c = nf*16 + lr;
                gl[nf] = ln1g[c]; bl[nf] = ln1b[c];
                float bb = wvb[c];
                #pragma unroll
                for (int i = 0; i < 4; ++i)
                    h[nf][i] = 0.5f*(acc[nf][i] + bb) + 0.5f*h[nf][i];
            }
            #pragma unroll
            for (int i = 0; i < 4; ++i) {
                float s = 0.f, s2 = 0.f;
                #pragma unroll
                for (int nf = 0; nf < 8; ++nf) { s += h[nf][i]; s2 += h[nf][i]*h[nf][i]; }
                #pragma unroll
                for (int m = 1; m < 16; m <<= 1) { s += __shfl_xor(s, m); s2 += __shfl_xor(s2, m); }
                float mean = s * (1.f/128.f);
                float inv  = rsqrtf(s2 * (1.f/128.f) - mean*mean + EPSF);
                int rbase = row0 + w*16 + lg*4 + i;
                #pragma unroll
                for (int nf = 0; nf < 8; ++nf) {
                    float v = fmaxf((h[nf][i]-mean)*inv*gl[nf] + bl[nf], 0.f);
                    if (rbase < nrows)
                        XTb[(size_t)rbase*128 + nf*16 + lr] = bf16u(v);
                }
            }
        }
        __syncthreads();                              // (3) Acur reads done; Anxt visible
        par = !par;
    }
}

// ---------------------------------------------------------------------------
// MFMA GEMM (GNN layer 1): C = BN_relu(A@W+bias) + resid. R13 verbatim.
// ---------------------------------------------------------------------------
__global__ __launch_bounds__(256)
void mgemm(const unsigned short* __restrict__ Ab16, const unsigned short* __restrict__ WTf,
           const float* __restrict__ bias, float* __restrict__ Cf,
           unsigned short* __restrict__ Cb, int nrows,
           const float* __restrict__ p0, const float* __restrict__ p1,
           const float* __restrict__ p2, const float* __restrict__ p3,
           const float* __restrict__ resid)
{
    __shared__ __align__(16) char lds[50176];
    char*  Ar  = lds;
    char*  Wr  = lds + 16384;
    float* Cst = (float*)Wr;
    const int tid  = threadIdx.x;
    const int row0 = blockIdx.x * 64;
    const int w  = tid >> 6, ln = tid & 63, lr = ln & 15, lg = ln >> 4;
    const int ksw = (lr & 7) << 4;

    #pragma unroll
    for (int i = 0; i < 4; ++i) {
        int c  = tid + i*256, r = c >> 4, k0 = (c & 15)*8;
        uint4 v = make_uint4(0,0,0,0);
        if (row0 + r < nrows)
            v = *(const uint4*)&Ab16[(size_t)(row0+r)*128 + k0];
        *(uint4*)&Ar[r*256 + ((k0*2) ^ ((r&7)<<4))] = v;
    }
    #pragma unroll
    for (int i = 0; i < 8; ++i) {
        int c = tid + i*256;
        *(uint4*)&Wr[c*16] = *(const uint4*)&WTf[c*8];
    }
    __syncthreads();

    const char* Abase = &Ar[(w*16 + lr)*256];
    f32x4 acc[8];
    #pragma unroll
    for (int nf = 0; nf < 8; ++nf) acc[nf] = (f32x4){0.f,0.f,0.f,0.f};
    #pragma unroll
    for (int ks = 0; ks < 4; ++ks) {
        int kb = ks*64 + lg*16;
        bfx8 a = lds_ld(Abase + (kb ^ ksw));
        #pragma unroll
        for (int nf = 0; nf < 8; ++nf) {
            bfx8 b = lds_ld(&Wr[(nf*4+ks)*1024 + ln*16]);
            acc[nf] = __builtin_amdgcn_mfma_f32_16x16x32_bf16(a, b, acc[nf], 0, 0, 0);
        }
    }

    float t[8][4];
    #pragma unroll
    for (int nf = 0; nf < 8; ++nf) {
        int c = nf*16 + lr;
        float sc = p0[c] * rsqrtf(p3[c] + EPSF);
        float sh = p1[c] - p2[c]*sc;
        float bb = bias[c];
        #pragma unroll
        for (int i = 0; i < 4; ++i)
            t[nf][i] = fmaxf((acc[nf][i] + bb)*sc + sh, 0.f);
    }

    __syncthreads();
    #pragma unroll
    for (int nf = 0; nf < 8; ++nf)
        #pragma unroll
        for (int i = 0; i < 4; ++i)
            Cst[(w*16 + lg*4 + i)*132 + nf*16 + lr] = t[nf][i];
    __syncthreads();
    #pragma unroll
    for (int i = 0; i < 8; ++i) {
        int c = tid + i*256, r = c >> 5, c4 = (c & 31)*4;
        if (row0 + r >= nrows) continue;
        f32x4 v = *(f32x4*)&Cst[r*132 + c4];
        float4 rr = ld4(resid + (size_t)(row0+r)*128 + c4);
        v.x += rr.x; v.y += rr.y; v.z += rr.z; v.w += rr.w;
        *(f32x4*)&Cf[(size_t)(row0+r)*128 + c4] = v;
        uint2 pk;
        pk.x = f2bf(v.x) | (f2bf(v.y) << 16);
        pk.y = f2bf(v.z) | (f2bf(v.w) << 16);
        *(uint2*)&Cb[(size_t)(row0+r)*128 + c4] = pk;
    }
}

// ---------------------------------------------------------------------------
// MFMA GEMM layer 2 + fused OUTPUT GEMM (R14 verbatim):
//   G2 = BN_relu(A@Wg2+bias) + resid  (on-chip, bf16-rounded)
//   out = tanh( [XT | G2] @ Wout + B )
// ---------------------------------------------------------------------------
__global__ __launch_bounds__(256)
void mgemm_out(const unsigned short* __restrict__ Ab16,
               const unsigned short* __restrict__ WTf,
               const float* __restrict__ bias,
               const float* __restrict__ p0, const float* __restrict__ p1,
               const float* __restrict__ p2, const float* __restrict__ p3,
               const float* __restrict__ resid,
               const unsigned short* __restrict__ XTb,
               const unsigned short* __restrict__ WToutf,
               const float* __restrict__ outB,
               float* __restrict__ out, int nrows)
{
    __shared__ __align__(16) char lds[65536];
    char* Ar  = lds;
    char* Wg  = lds + 16384;
    char* WrX = lds + 16384;
    char* WrO = lds + 32768;
    const int tid  = threadIdx.x;
    const int row0 = blockIdx.x * 64;
    const int w  = tid >> 6, ln = tid & 63, lr = ln & 15, lg = ln >> 4;
    const int ksw = (lr & 7) << 4;

    #pragma unroll
    for (int i = 0; i < 4; ++i) {
        int c  = tid + i*256, r = c >> 4, k0 = (c & 15)*8;
        uint4 v = make_uint4(0,0,0,0);
        if (row0 + r < nrows)
            v = *(const uint4*)&Ab16[(size_t)(row0+r)*128 + k0];
        *(uint4*)&Ar[r*256 + ((k0*2) ^ ((r&7)<<4))] = v;
    }
    #pragma unroll
    for (int i = 0; i < 8; ++i) {
        int c = tid + i*256;
        *(uint4*)&Wg[c*16] = *(const uint4*)&WTf[c*8];
    }
    __syncthreads();

    const char* Abase = &Ar[(w*16 + lr)*256];
    f32x4 acc[8];
    #pragma unroll
    for (int nf = 0; nf < 8; ++nf) acc[nf] = (f32x4){0.f,0.f,0.f,0.f};
    #pragma unroll
    for (int ks = 0; ks < 4; ++ks) {
        int kb = ks*64 + lg*16;
        bfx8 a = lds_ld(Abase + (kb ^ ksw));
        #pragma unroll
        for (int nf = 0; nf < 8; ++nf) {
            bfx8 b = lds_ld(&Wg[(nf*4+ks)*1024 + ln*16]);
            acc[nf] = __builtin_amdgcn_mfma_f32_16x16x32_bf16(a, b, acc[nf], 0, 0, 0);
        }
    }
    float t[8][4];
    #pragma unroll
    for (int nf = 0; nf < 8; ++nf) {
        int c = nf*16 + lr;
        float sc = p0[c] * rsqrtf(p3[c] + EPSF);
        float sh = p1[c] - p2[c]*sc;
        float bb = bias[c];
        #pragma unroll
        for (int i = 0; i < 4; ++i) {
            int r = row0 + w*16 + lg*4 + i;
            float rv = (r < nrows) ? resid[(size_t)r*128 + c] : 0.f;
            t[nf][i] = fmaxf((acc[nf][i] + bb)*sc + sh, 0.f) + rv;
        }
    }
    __syncthreads();

    #pragma unroll
    for (int nf = 0; nf < 8; ++nf) {
        int c = nf*16 + lr;
        #pragma unroll
        for (int i = 0; i < 4; ++i) {
            int r = w*16 + lg*4 + i;
            *(unsigned short*)&Ar[(r*256 + c*2) ^ ((r&7)<<4)] = bf16u(t[nf][i]);
        }
    }
    #pragma unroll
    for (int i = 0; i < 4; ++i) {
        int c  = tid + i*256, r = c >> 4, k0 = (c & 15)*8;
        uint4 v = make_uint4(0,0,0,0);
        if (row0 + r < nrows)
            v = *(const uint4*)&XTb[(size_t)(row0+r)*128 + k0];
        *(uint4*)&WrX[r*256 + ((k0*2) ^ ((r&7)<<4))] = v;
    }
    #pragma unroll
    for (int i = 0; i < 8; ++i) {
        int c = tid + i*256;
        *(uint4*)&WrO[c*16] = *(const uint4*)&WToutf[c*8];
    }
    __syncthreads();

    f32x4 acc2[4];
    #pragma unroll
    for (int nf = 0; nf < 4; ++nf) acc2[nf] = (f32x4){0.f,0.f,0.f,0.f};
    const char* Xbase = &WrX[(w*16 + lr)*256];
    #pragma unroll
    for (int ks = 0; ks < 8; ++ks) {
        int kb = (ks & 3)*64 + lg*16;
        bfx8 a = (ks < 4) ? lds_ld(Xbase + (kb ^ ksw))
                          : lds_ld(Abase + (kb ^ ksw));
        #pragma unroll
        for (int nf = 0; nf < 4; ++nf) {
            bfx8 b = lds_ld(&WrO[(nf*8+ks)*1024 + ln*16]);
            acc2[nf] = __builtin_amdgcn_mfma_f32_16x16x32_bf16(a, b, acc2[nf], 0, 0, 0);
        }
    }
    #pragma unroll
    for (int nf = 0; nf < 4; ++nf) {
        float bb = outB[nf*16 + lr];
        #pragma unroll
        for (int i = 0; i < 4; ++i) {
            int r = row0 + w*16 + lg*4 + i;
            if (r < nrows)
                out[(size_t)r*64 + nf*16 + lr] = tanhf(acc2[nf][i] + bb);
        }
    }
}

// ---------------------------------------------------------------------------
// CSR build: histogram -> multi-block scan (packed {cnt,off}) -> fill.
// ---------------------------------------------------------------------------
__global__ __launch_bounds__(256)
void edge_hist(const int* __restrict__ col, const int* __restrict__ et,
               int* __restrict__ cnt, int* __restrict__ ePos, int n, int ne)
{
    int e = blockIdx.x*256 + threadIdx.x;
    if (e >= ne) return;
    int pos = atomicAdd(&cnt[et[e]*n + col[e]], 1);
    ePos[e] = pos;
}

__global__ __launch_bounds__(1024)
void scan_block(const int* __restrict__ cnt, int2* __restrict__ co,
                int* __restrict__ bsum, int n)
{
    __shared__ int s[1024];
    const int t = threadIdx.x;
    const int i = blockIdx.x*1024 + t;
    int v = (i < n) ? cnt[i] : 0;
    s[t] = v;
    __syncthreads();
    #pragma unroll
    for (int d = 1; d < 1024; d <<= 1) {
        int u = (t >= d) ? s[t-d] : 0;
        __syncthreads();
        s[t] += u;
        __syncthreads();
    }
    if (i < n) co[i] = make_int2(v, s[t] - v);
    if (t == 1023) bsum[blockIdx.x] = s[1023];
}

__global__ __launch_bounds__(256)
void scan_bsums(int* __restrict__ bsum, int nb)
{
    __shared__ int s[256];
    const int t = threadIdx.x;
    int v = (t < nb) ? bsum[t] : 0;
    s[t] = v;
    __syncthreads();
    #pragma unroll
    for (int d = 1; d < 256; d <<= 1) {
        int u = (t >= d) ? s[t-d] : 0;
        __syncthreads();
        s[t] += u;
        __syncthreads();
    }
    if (t < nb) bsum[t] = s[t] - v;
}

__global__ __launch_bounds__(256)
void edge_fill(const int* __restrict__ row_idx, const int* __restrict__ col_idx,
               const int* __restrict__ et, const float* __restrict__ ew,
               const int2* __restrict__ co, const int* __restrict__ bsum,
               const int* __restrict__ ePos,
               uint2* __restrict__ ePack, int n, int ne)
{
    int e = blockIdx.x*256 + threadIdx.x;
    if (e >= ne) return;
    int t = et[e], c = col_idx[e], r = row_idx[e];
    int ic = t*n + c;
    int2 qc = co[ic];
    int2 qr = co[t*n + r];
    int idx = qc.y + bsum[ic >> 10] + ePos[e];
    int p = qc.x * qr.x;
    float val = (p > 0) ? ew[e] * rsqrtf((float)p) : 0.f;
    ePack[idx] = make_uint2((unsigned)r, __builtin_bit_cast(unsigned, val));
}

// ---------------------------------------------------------------------------
// CSR gather (bf16 in, bf16 out): one wave per node, lane = 2 feature cols.
// ---------------------------------------------------------------------------
__global__ __launch_bounds__(256)
void hetero_gather(const unsigned short* __restrict__ Gb,
                   const uint2* __restrict__ ePack,
                   const int2* __restrict__ co, const int* __restrict__ bsum,
                   int t0, unsigned short* __restrict__ AGGb, int n)
{
    int node = blockIdx.x*4 + (threadIdx.x >> 6);
    if (node >= n) return;
    const int lane = threadIdx.x & 63;
    const int gi   = t0 + node;
    int2 q = co[gi];
    const int base = q.y + bsum[gi >> 10];
    const int m = q.x;
    float ax = 0.f, ay = 0.f;
    int i = 0;
    for (; i + 3 < m; i += 4) {
        uint2 q0 = ePack[base+i];
        uint2 q1 = ePack[base+i+1];
        uint2 q2 = ePack[base+i+2];
        uint2 q3 = ePack[base+i+3];
        unsigned g0 = *(const unsigned*)&Gb[(size_t)q0.x*128 + lane*2];
        unsigned g1 = *(const unsigned*)&Gb[(size_t)q1.x*128 + lane*2];
        unsigned g2 = *(const unsigned*)&Gb[(size_t)q2.x*128 + lane*2];
        unsigned g3 = *(const unsigned*)&Gb[(size_t)q3.x*128 + lane*2];
        float v0 = __builtin_bit_cast(float, q0.y);
        float v1 = __builtin_bit_cast(float, q1.y);
        float v2 = __builtin_bit_cast(float, q2.y);
        float v3 = __builtin_bit_cast(float, q3.y);
        ax += v0*bf2f(g0 & 0xffff) + v1*bf2f(g1 & 0xffff)
            + v2*bf2f(g2 & 0xffff) + v3*bf2f(g3 & 0xffff);
        ay += v0*bf2f(g0 >> 16)    + v1*bf2f(g1 >> 16)
            + v2*bf2f(g2 >> 16)    + v3*bf2f(g3 >> 16);
    }
    for (; i < m; ++i) {
        uint2 q0 = ePack[base+i];
        unsigned g0 = *(const unsigned*)&Gb[(size_t)q0.x*128 + lane*2];
        float v0 = __builtin_bit_cast(float, q0.y);
        ax += v0*bf2f(g0 & 0xffff);
        ay += v0*bf2f(g0 >> 16);
    }
    unsigned pk = f2bf(ax) | (f2bf(ay) << 16);
    *(unsigned*)&AGGb[(size_t)node*128 + lane*2] = pk;
}

extern "C" void kernel_launch(void* const* d_in, const int* in_sizes, int n_in,
                              void* d_out, int out_size, void* d_ws, size_t ws_size,
                              hipStream_t stream)
{
    const float* x      = (const float*)d_in[0];
    const float* ew     = (const float*)d_in[1];
    const float* t_fc_w = (const float*)d_in[2];
    const float* t_fc_b = (const float*)d_in[3];
    const float* ln0g   = (const float*)d_in[4];
    const float* ln0b   = (const float*)d_in[5];
    const float* wvw    = (const float*)d_in[10];
    const float* wvb    = (const float*)d_in[11];
    const float* ln1g   = (const float*)d_in[12];
    const float* ln1b   = (const float*)d_in[13];
    const float* gfcw   = (const float*)d_in[14];
    const float* gfcb   = (const float*)d_in[15];
    const float* bn0g   = (const float*)d_in[16];
    const float* bn0b   = (const float*)d_in[17];
    const float* bn0m   = (const float*)d_in[18];
    const float* bn0v   = (const float*)d_in[19];
    const float* gw1    = (const float*)d_in[20];
    const float* gb1    = (const float*)d_in[21];
    const float* bn1g   = (const float*)d_in[22];
    const float* bn1b   = (const float*)d_in[23];
    const float* bn1m   = (const float*)d_in[24];
    const float* bn1v   = (const float*)d_in[25];
    const float* gw2    = (const float*)d_in[26];
    const float* gb2    = (const float*)d_in[27];
    const float* bn2g   = (const float*)d_in[28];
    const float* bn2b   = (const float*)d_in[29];
    const float* bn2m   = (const float*)d_in[30];
    const float* bn2v   = (const float*)d_in[31];
    const float* outw   = (const float*)d_in[32];
    const float* outb   = (const float*)d_in[33];
    const int*   ei     = (const int*)d_in[34];
    const int*   et     = (const int*)d_in[35];

    const int N = 100000, E = 800000;
    const size_t NF = (size_t)N*128;
    float* F1 = (float*)d_ws;                         // G1 f32 (resid for g2)
    float* F2 = F1 + NF;                              // G  f32 (resid for g1)
    unsigned short* B1 = (unsigned short*)(F2 + NF);  // AGG0 / AGG1
    unsigned short* B3 = B1 + NF;                     // Gb -> G1b
    unsigned short* B4 = B3 + NF;                     // XTb
    unsigned short* WT = B4 + NF;                     // fragment-layout weights
    unsigned short* wt_tfc = WT;
    unsigned short* wt_wv  = WT + 16384;
    unsigned short* wt_gfc = WT + 2*16384;
    unsigned short* wt_g1  = WT + 3*16384;
    unsigned short* wt_g2  = WT + 4*16384;
    unsigned short* wt_out = WT + 5*16384;
    int*   cnt    = (int*)(WT + 6*16384);             // [2N]
    int2*  co     = (int2*)(cnt + 2*N);               // [2N] {cnt, local off}
    int*   ePos   = (int*)(co + 2*N);                 // [E]
    uint2* ePack  = (uint2*)(ePos + E);               // [E]
    int*   bsum   = (int*)(ePack + E);                // [256]

    dim3 blk(256);
    const int nb64 = (N + 63) / 64;
    const int* row_idx = ei;
    const int* col_idx = ei + E;
    const int nscan = 2*N;
    const int nsb = (nscan + 1023) / 1024;

    // --- CSR build ---
    hipMemsetAsync(cnt, 0, 2*(size_t)N*sizeof(int), stream);
    edge_hist<<<(E + 255)/256, blk, 0, stream>>>(col_idx, et, cnt, ePos, N, E);
    scan_block<<<nsb, 1024, 0, stream>>>(cnt, co, bsum, nscan);
    scan_bsums<<<1, 256, 0, stream>>>(bsum, nsb);
    edge_fill<<<(E + 255)/256, blk, 0, stream>>>(row_idx, col_idx, et, ew,
                                                 co, bsum, ePos, ePack, N, E);

    // --- weights -> bf16 fragment layout ---
    wconv_all<<<48, blk, 0, stream>>>(t_fc_w, wvw, gfcw, gw1, gw2, outw, WT);

    // --- persistent fused front end: XTb, G(f32), Gb ---
    fused_front<<<256, blk, 0, stream>>>(x, wt_tfc, wt_wv, wt_gfc,
        t_fc_b, ln0g, ln0b, wvb, ln1g, ln1b,
        gfcb, bn0g, bn0b, bn0m, bn0v, B4, F2, B3, N, nb64);

    // --- GNN chain (layer2 GEMM fused with output GEMM) ---
    hetero_gather<<<(N + 3)/4, blk, 0, stream>>>(B3, ePack, co, bsum, 0, B1, N);
    mgemm<<<nb64, blk, 0, stream>>>(B1, wt_g1, gb1, F1, B3, N,
                                    bn1g, bn1b, bn1m, bn1v, F2);
    hetero_gather<<<(N + 3)/4, blk, 0, stream>>>(B3, ePack, co, bsum, N, B1, N);
    mgemm_out<<<nb64, blk, 0, stream>>>(B1, wt_g2, gb2,
        bn2g, bn2b, bn2m, bn2v, F1, B4, wt_out, outb, (float*)d_out, N);
}

// Round 16
// 275.405 us; speedup vs baseline: 1.0556x; 1.0556x over previous
//
#include <hip/hip_runtime.h>
#include <cmath>

#define EPSF 1e-5f

typedef __bf16 bfx8 __attribute__((ext_vector_type(8)));
typedef float  f32x4 __attribute__((ext_vector_type(4)));

__device__ __forceinline__ float4 ld4(const float* p){ return *(const float4*)p; }
__device__ __forceinline__ unsigned f2bf(float f){
    unsigned u = __builtin_bit_cast(unsigned, f);
    return (u + 0x7FFFu + ((u >> 16) & 1u)) >> 16;
}
__device__ __forceinline__ float bf2f(unsigned u){
    return __builtin_bit_cast(float, u << 16);
}
__device__ __forceinline__ bfx8 lds_ld(const char* p){ return *(const bfx8*)p; }
__device__ __forceinline__ unsigned short bf16u(float f){ return (unsigned short)f2bf(f); }

// ---------------------------------------------------------------------------
// weights -> bf16 FRAGMENT layout in global (B staging = pure linear copy):
//   seg<5 (128x128): chunk=(nf*4+ks)*64+ln, elem j = W[k][c],
//       c=nf*16+(ln&15), k=ks*32+(ln>>4)*8+j
//   seg5  (256x64):  chunk=(nf*8+ks)*64+ln, same with 64 cols.
// ---------------------------------------------------------------------------
__global__ __launch_bounds__(256)
void wconv_all(const float* __restrict__ s0, const float* __restrict__ s1,
               const float* __restrict__ s2, const float* __restrict__ s3,
               const float* __restrict__ s4, const float* __restrict__ s5,
               unsigned short* __restrict__ WT)
{
    int gid   = blockIdx.x*256 + threadIdx.x;
    int seg   = gid >> 11;
    int chunk = gid & 2047;
    int ln    = chunk & 63;
    unsigned short tmp[8];
    if (seg < 5) {
        const float* s = seg==0?s0: seg==1?s1: seg==2?s2: seg==3?s3: s4;
        int nf = chunk >> 8, ks = (chunk >> 6) & 3;
        int c  = nf*16 + (ln & 15);
        int k0 = ks*32 + (ln >> 4)*8;
        #pragma unroll
        for (int j = 0; j < 8; ++j) tmp[j] = bf16u(s[(size_t)(k0+j)*128 + c]);
        *(uint4*)&WT[seg*16384 + chunk*8] = *(uint4*)tmp;
    } else {
        int nf = chunk >> 9, ks = (chunk >> 6) & 7;
        int c  = nf*16 + (ln & 15);
        int k0 = ks*32 + (ln >> 4)*8;
        #pragma unroll
        for (int j = 0; j < 8; ++j) tmp[j] = bf16u(s5[(size_t)(k0+j)*64 + c]);
        *(uint4*)&WT[5*16384 + chunk*8] = *(uint4*)tmp;
    }
}

// ---------------------------------------------------------------------------
// fused front end v13 (measured 62us): 256 threads / 4 waves, wave owns 16
// full rows (LN in-wave), DUAL weight regions staged in phase 0.
//   H = relu(LN(x@tfc+b)); G = relu(BN(x@gfc+b)) -> Gf,Gb
//   V = H@wv+b; XT = relu(LN(.5V+.5H)) -> XTb
//   [attention term ~1e-8, dropped: q,k normalized by GLOBAL Frobenius norm]
// LDS 80K: Ar 16K (x -> H, XOR) | WrA 32K (tfc -> wv) | WrB 32K (gfc -> Cst)
// ---------------------------------------------------------------------------
__global__ __launch_bounds__(256)
void fused_front(const float* __restrict__ x,
                 const unsigned short* __restrict__ wt_tfc,
                 const unsigned short* __restrict__ wt_wv,
                 const unsigned short* __restrict__ wt_gfc,
                 const float* __restrict__ tfcb, const float* __restrict__ ln0g,
                 const float* __restrict__ ln0b, const float* __restrict__ wvb,
                 const float* __restrict__ ln1g, const float* __restrict__ ln1b,
                 const float* __restrict__ gfcb, const float* __restrict__ bn0g,
                 const float* __restrict__ bn0b, const float* __restrict__ bn0m,
                 const float* __restrict__ bn0v,
                 unsigned short* __restrict__ XTb, float* __restrict__ Gf,
                 unsigned short* __restrict__ Gb, int nrows)
{
    __shared__ __align__(16) char lds[81920];
    char*  Ar  = lds;
    char*  WrA = lds + 16384;
    char*  WrB = lds + 49152;
    float* Cst = (float*)WrB;
    const int tid  = threadIdx.x;
    const int row0 = blockIdx.x * 64;
    const int w  = tid >> 6, ln = tid & 63, lr = ln & 15, lg = ln >> 4;
    const int ksw = (lr & 7) << 4;

    #pragma unroll
    for (int i = 0; i < 4; ++i) {
        int c  = tid + i*256, r = c >> 4, k0 = (c & 15)*8;
        uint4 v4 = make_uint4(0,0,0,0);
        if (row0 + r < nrows) {
            float4 f0 = ld4(&x[(size_t)(row0+r)*128 + k0]);
            float4 f1 = ld4(&x[(size_t)(row0+r)*128 + k0 + 4]);
            v4.x = f2bf(f0.x) | (f2bf(f0.y) << 16);
            v4.y = f2bf(f0.z) | (f2bf(f0.w) << 16);
            v4.z = f2bf(f1.x) | (f2bf(f1.y) << 16);
            v4.w = f2bf(f1.z) | (f2bf(f1.w) << 16);
        }
        *(uint4*)&Ar[r*256 + ((k0*2) ^ ((r&7)<<4))] = v4;
    }
    #pragma unroll
    for (int i = 0; i < 8; ++i) {
        int c = tid + i*256;
        *(uint4*)&WrA[c*16] = *(const uint4*)&wt_tfc[c*8];
    }
    #pragma unroll
    for (int i = 0; i < 8; ++i) {
        int c = tid + i*256;
        *(uint4*)&WrB[c*16] = *(const uint4*)&wt_gfc[c*8];
    }
    __syncthreads();                                      // (1)

    const char* Abase = &Ar[(w*16 + lr)*256];
    f32x4 acc[8];
    float h[8][4];

    #pragma unroll
    for (int nf = 0; nf < 8; ++nf) acc[nf] = (f32x4){0.f,0.f,0.f,0.f};
    #pragma unroll
    for (int ks = 0; ks < 4; ++ks) {
        int kb = ks*64 + lg*16;
        bfx8 a = lds_ld(Abase + (kb ^ ksw));
        #pragma unroll
        for (int nf = 0; nf < 8; ++nf) {
            bfx8 b = lds_ld(&WrA[(nf*4+ks)*1024 + ln*16]);
            acc[nf] = __builtin_amdgcn_mfma_f32_16x16x32_bf16(a, b, acc[nf], 0, 0, 0);
        }
    }
    {
        float gl[8], bl[8];
        #pragma unroll
        for (int nf = 0; nf < 8; ++nf) {
            int c = nf*16 + lr;
            gl[nf] = ln0g[c]; bl[nf] = ln0b[c];
            float bb = tfcb[c];
            #pragma unroll
            for (int i = 0; i < 4; ++i) h[nf][i] = acc[nf][i] + bb;
        }
        #pragma unroll
        for (int i = 0; i < 4; ++i) {
            float s = 0.f, s2 = 0.f;
            #pragma unroll
            for (int nf = 0; nf < 8; ++nf) { s += h[nf][i]; s2 += h[nf][i]*h[nf][i]; }
            #pragma unroll
            for (int m = 1; m < 16; m <<= 1) { s += __shfl_xor(s, m); s2 += __shfl_xor(s2, m); }
            float mean = s * (1.f/128.f);
            float inv  = rsqrtf(s2 * (1.f/128.f) - mean*mean + EPSF);
            #pragma unroll
            for (int nf = 0; nf < 8; ++nf)
                h[nf][i] = fmaxf((h[nf][i]-mean)*inv*gl[nf] + bl[nf], 0.f);
        }
    }
    #pragma unroll
    for (int nf = 0; nf < 8; ++nf) acc[nf] = (f32x4){0.f,0.f,0.f,0.f};
    #pragma unroll
    for (int ks = 0; ks < 4; ++ks) {
        int kb = ks*64 + lg*16;
        bfx8 a = lds_ld(Abase + (kb ^ ksw));
        #pragma unroll
        for (int nf = 0; nf < 8; ++nf) {
            bfx8 b = lds_ld(&WrB[(nf*4+ks)*1024 + ln*16]);
            acc[nf] = __builtin_amdgcn_mfma_f32_16x16x32_bf16(a, b, acc[nf], 0, 0, 0);
        }
    }
    #pragma unroll
    for (int nf = 0; nf < 8; ++nf) {
        int c = nf*16 + lr;
        float sc = bn0g[c] * rsqrtf(bn0v[c] + EPSF);
        float sh = bn0b[c] - bn0m[c]*sc;
        float bb = gfcb[c];
        #pragma unroll
        for (int i = 0; i < 4; ++i)
            acc[nf][i] = fmaxf((acc[nf][i] + bb)*sc + sh, 0.f);
    }
    __syncthreads();                                      // (2)

    #pragma unroll
    for (int nf = 0; nf < 8; ++nf) {
        int c = nf*16 + lr;
        #pragma unroll
        for (int i = 0; i < 4; ++i) {
            int r = w*16 + lg*4 + i;
            Cst[r*128 + c] = acc[nf][i];
            *(unsigned short*)&Ar[(r*256 + c*2) ^ ((r&7)<<4)] = bf16u(h[nf][i]);
        }
    }
    #pragma unroll
    for (int i = 0; i < 8; ++i) {
        int c = tid + i*256;
        *(uint4*)&WrA[c*16] = *(const uint4*)&wt_wv[c*8];
    }
    __syncthreads();                                      // (3)

    #pragma unroll
    for (int i = 0; i < 8; ++i) {
        int c = tid + i*256, r = c >> 5, k4 = (c & 31)*4;
        if (row0 + r < nrows) {
            f32x4 v = *(f32x4*)&Cst[r*128 + k4];
            *(f32x4*)&Gf[(size_t)(row0+r)*128 + k4] = v;
            uint2 pk;
            pk.x = f2bf(v[0]) | (f2bf(v[1]) << 16);
            pk.y = f2bf(v[2]) | (f2bf(v[3]) << 16);
            *(uint2*)&Gb[(size_t)(row0+r)*128 + k4] = pk;
        }
    }
    #pragma unroll
    for (int nf = 0; nf < 8; ++nf) acc[nf] = (f32x4){0.f,0.f,0.f,0.f};
    #pragma unroll
    for (int ks = 0; ks < 4; ++ks) {
        int kb = ks*64 + lg*16;
        bfx8 a = lds_ld(Abase + (kb ^ ksw));
        #pragma unroll
        for (int nf = 0; nf < 8; ++nf) {
            bfx8 b = lds_ld(&WrA[(nf*4+ks)*1024 + ln*16]);
            acc[nf] = __builtin_amdgcn_mfma_f32_16x16x32_bf16(a, b, acc[nf], 0, 0, 0);
        }
    }
    {
        float gl[8], bl[8];
        #pragma unroll
        for (int nf = 0; nf < 8; ++nf) {
            int c = nf*16 + lr;
            gl[nf] = ln1g[c]; bl[nf] = ln1b[c];
            float bb = wvb[c];
            #pragma unroll
            for (int i = 0; i < 4; ++i)
                h[nf][i] = 0.5f*(acc[nf][i] + bb) + 0.5f*h[nf][i];
        }
        #pragma unroll
        for (int i = 0; i < 4; ++i) {
            float s = 0.f, s2 = 0.f;
            #pragma unroll
            for (int nf = 0; nf < 8; ++nf) { s += h[nf][i]; s2 += h[nf][i]*h[nf][i]; }
            #pragma unroll
            for (int m = 1; m < 16; m <<= 1) { s += __shfl_xor(s, m); s2 += __shfl_xor(s2, m); }
            float mean = s * (1.f/128.f);
            float inv  = rsqrtf(s2 * (1.f/128.f) - mean*mean + EPSF);
            #pragma unroll
            for (int nf = 0; nf < 8; ++nf)
                h[nf][i] = fmaxf((h[nf][i]-mean)*inv*gl[nf] + bl[nf], 0.f);
        }
    }
    __syncthreads();                                      // (4)

    #pragma unroll
    for (int nf = 0; nf < 8; ++nf) {
        int c = nf*16 + lr;
        #pragma unroll
        for (int i = 0; i < 4; ++i)
            Cst[(w*16 + lg*4 + i)*128 + c] = h[nf][i];
    }
    __syncthreads();                                      // (5)
    #pragma unroll
    for (int i = 0; i < 8; ++i) {
        int c = tid + i*256, r = c >> 5, k4 = (c & 31)*4;
        if (row0 + r < nrows) {
            f32x4 v = *(f32x4*)&Cst[r*128 + k4];
            uint2 pk;
            pk.x = f2bf(v[0]) | (f2bf(v[1]) << 16);
            pk.y = f2bf(v[2]) | (f2bf(v[3]) << 16);
            *(uint2*)&XTb[(size_t)(row0+r)*128 + k4] = pk;
        }
    }
}

// ---------------------------------------------------------------------------
// MFMA GEMM (GNN layer 1): C = BN_relu(A@W+bias) + resid.
// ---------------------------------------------------------------------------
__global__ __launch_bounds__(256)
void mgemm(const unsigned short* __restrict__ Ab16, const unsigned short* __restrict__ WTf,
           const float* __restrict__ bias, float* __restrict__ Cf,
           unsigned short* __restrict__ Cb, int nrows,
           const float* __restrict__ p0, const float* __restrict__ p1,
           const float* __restrict__ p2, const float* __restrict__ p3,
           const float* __restrict__ resid)
{
    __shared__ __align__(16) char lds[50176];
    char*  Ar  = lds;
    char*  Wr  = lds + 16384;
    float* Cst = (float*)Wr;
    const int tid  = threadIdx.x;
    const int row0 = blockIdx.x * 64;
    const int w  = tid >> 6, ln = tid & 63, lr = ln & 15, lg = ln >> 4;
    const int ksw = (lr & 7) << 4;

    #pragma unroll
    for (int i = 0; i < 4; ++i) {
        int c  = tid + i*256, r = c >> 4, k0 = (c & 15)*8;
        uint4 v = make_uint4(0,0,0,0);
        if (row0 + r < nrows)
            v = *(const uint4*)&Ab16[(size_t)(row0+r)*128 + k0];
        *(uint4*)&Ar[r*256 + ((k0*2) ^ ((r&7)<<4))] = v;
    }
    #pragma unroll
    for (int i = 0; i < 8; ++i) {
        int c = tid + i*256;
        *(uint4*)&Wr[c*16] = *(const uint4*)&WTf[c*8];
    }
    __syncthreads();

    const char* Abase = &Ar[(w*16 + lr)*256];
    f32x4 acc[8];
    #pragma unroll
    for (int nf = 0; nf < 8; ++nf) acc[nf] = (f32x4){0.f,0.f,0.f,0.f};
    #pragma unroll
    for (int ks = 0; ks < 4; ++ks) {
        int kb = ks*64 + lg*16;
        bfx8 a = lds_ld(Abase + (kb ^ ksw));
        #pragma unroll
        for (int nf = 0; nf < 8; ++nf) {
            bfx8 b = lds_ld(&Wr[(nf*4+ks)*1024 + ln*16]);
            acc[nf] = __builtin_amdgcn_mfma_f32_16x16x32_bf16(a, b, acc[nf], 0, 0, 0);
        }
    }

    float t[8][4];
    #pragma unroll
    for (int nf = 0; nf < 8; ++nf) {
        int c = nf*16 + lr;
        float sc = p0[c] * rsqrtf(p3[c] + EPSF);
        float sh = p1[c] - p2[c]*sc;
        float bb = bias[c];
        #pragma unroll
        for (int i = 0; i < 4; ++i)
            t[nf][i] = fmaxf((acc[nf][i] + bb)*sc + sh, 0.f);
    }

    __syncthreads();
    #pragma unroll
    for (int nf = 0; nf < 8; ++nf)
        #pragma unroll
        for (int i = 0; i < 4; ++i)
            Cst[(w*16 + lg*4 + i)*132 + nf*16 + lr] = t[nf][i];
    __syncthreads();
    #pragma unroll
    for (int i = 0; i < 8; ++i) {
        int c = tid + i*256, r = c >> 5, c4 = (c & 31)*4;
        if (row0 + r >= nrows) continue;
        f32x4 v = *(f32x4*)&Cst[r*132 + c4];
        float4 rr = ld4(resid + (size_t)(row0+r)*128 + c4);
        v.x += rr.x; v.y += rr.y; v.z += rr.z; v.w += rr.w;
        *(f32x4*)&Cf[(size_t)(row0+r)*128 + c4] = v;
        uint2 pk;
        pk.x = f2bf(v.x) | (f2bf(v.y) << 16);
        pk.y = f2bf(v.z) | (f2bf(v.w) << 16);
        *(uint2*)&Cb[(size_t)(row0+r)*128 + c4] = pk;
    }
}

// ---------------------------------------------------------------------------
// MFMA GEMM layer 2 + fused OUTPUT GEMM:
//   G2 = BN_relu(A@Wg2+bias) + resid  (on-chip, bf16-rounded)
//   out = tanh( [XT | G2] @ Wout + B )
// ---------------------------------------------------------------------------
__global__ __launch_bounds__(256)
void mgemm_out(const unsigned short* __restrict__ Ab16,
               const unsigned short* __restrict__ WTf,
               const float* __restrict__ bias,
               const float* __restrict__ p0, const float* __restrict__ p1,
               const float* __restrict__ p2, const float* __restrict__ p3,
               const float* __restrict__ resid,
               const unsigned short* __restrict__ XTb,
               const unsigned short* __restrict__ WToutf,
               const float* __restrict__ outB,
               float* __restrict__ out, int nrows)
{
    __shared__ __align__(16) char lds[65536];
    char* Ar  = lds;
    char* Wg  = lds + 16384;
    char* WrX = lds + 16384;
    char* WrO = lds + 32768;
    const int tid  = threadIdx.x;
    const int row0 = blockIdx.x * 64;
    const int w  = tid >> 6, ln = tid & 63, lr = ln & 15, lg = ln >> 4;
    const int ksw = (lr & 7) << 4;

    #pragma unroll
    for (int i = 0; i < 4; ++i) {
        int c  = tid + i*256, r = c >> 4, k0 = (c & 15)*8;
        uint4 v = make_uint4(0,0,0,0);
        if (row0 + r < nrows)
            v = *(const uint4*)&Ab16[(size_t)(row0+r)*128 + k0];
        *(uint4*)&Ar[r*256 + ((k0*2) ^ ((r&7)<<4))] = v;
    }
    #pragma unroll
    for (int i = 0; i < 8; ++i) {
        int c = tid + i*256;
        *(uint4*)&Wg[c*16] = *(const uint4*)&WTf[c*8];
    }
    __syncthreads();

    const char* Abase = &Ar[(w*16 + lr)*256];
    f32x4 acc[8];
    #pragma unroll
    for (int nf = 0; nf < 8; ++nf) acc[nf] = (f32x4){0.f,0.f,0.f,0.f};
    #pragma unroll
    for (int ks = 0; ks < 4; ++ks) {
        int kb = ks*64 + lg*16;
        bfx8 a = lds_ld(Abase + (kb ^ ksw));
        #pragma unroll
        for (int nf = 0; nf < 8; ++nf) {
            bfx8 b = lds_ld(&Wg[(nf*4+ks)*1024 + ln*16]);
            acc[nf] = __builtin_amdgcn_mfma_f32_16x16x32_bf16(a, b, acc[nf], 0, 0, 0);
        }
    }
    float t[8][4];
    #pragma unroll
    for (int nf = 0; nf < 8; ++nf) {
        int c = nf*16 + lr;
        float sc = p0[c] * rsqrtf(p3[c] + EPSF);
        float sh = p1[c] - p2[c]*sc;
        float bb = bias[c];
        #pragma unroll
        for (int i = 0; i < 4; ++i) {
            int r = row0 + w*16 + lg*4 + i;
            float rv = (r < nrows) ? resid[(size_t)r*128 + c] : 0.f;
            t[nf][i] = fmaxf((acc[nf][i] + bb)*sc + sh, 0.f) + rv;
        }
    }
    __syncthreads();

    #pragma unroll
    for (int nf = 0; nf < 8; ++nf) {
        int c = nf*16 + lr;
        #pragma unroll
        for (int i = 0; i < 4; ++i) {
            int r = w*16 + lg*4 + i;
            *(unsigned short*)&Ar[(r*256 + c*2) ^ ((r&7)<<4)] = bf16u(t[nf][i]);
        }
    }
    #pragma unroll
    for (int i = 0; i < 4; ++i) {
        int c  = tid + i*256, r = c >> 4, k0 = (c & 15)*8;
        uint4 v = make_uint4(0,0,0,0);
        if (row0 + r < nrows)
            v = *(const uint4*)&XTb[(size_t)(row0+r)*128 + k0];
        *(uint4*)&WrX[r*256 + ((k0*2) ^ ((r&7)<<4))] = v;
    }
    #pragma unroll
    for (int i = 0; i < 8; ++i) {
        int c = tid + i*256;
        *(uint4*)&WrO[c*16] = *(const uint4*)&WToutf[c*8];
    }
    __syncthreads();

    f32x4 acc2[4];
    #pragma unroll
    for (int nf = 0; nf < 4; ++nf) acc2[nf] = (f32x4){0.f,0.f,0.f,0.f};
    const char* Xbase = &WrX[(w*16 + lr)*256];
    #pragma unroll
    for (int ks = 0; ks < 8; ++ks) {
        int kb = (ks & 3)*64 + lg*16;
        bfx8 a = (ks < 4) ? lds_ld(Xbase + (kb ^ ksw))
                          : lds_ld(Abase + (kb ^ ksw));
        #pragma unroll
        for (int nf = 0; nf < 4; ++nf) {
            bfx8 b = lds_ld(&WrO[(nf*8+ks)*1024 + ln*16]);
            acc2[nf] = __builtin_amdgcn_mfma_f32_16x16x32_bf16(a, b, acc2[nf], 0, 0, 0);
        }
    }
    #pragma unroll
    for (int nf = 0; nf < 4; ++nf) {
        float bb = outB[nf*16 + lr];
        #pragma unroll
        for (int i = 0; i < 4; ++i) {
            int r = row0 + w*16 + lg*4 + i;
            if (r < nrows)
                out[(size_t)r*64 + nf*16 + lr] = tanhf(acc2[nf][i] + bb);
        }
    }
}

// ---------------------------------------------------------------------------
// CSR build: histogram -> multi-block scan (packed {cnt,off}) -> fill.
// ---------------------------------------------------------------------------
__global__ __launch_bounds__(256)
void edge_hist(const int* __restrict__ col, const int* __restrict__ et,
               int* __restrict__ cnt, int* __restrict__ ePos, int n, int ne)
{
    int e = blockIdx.x*256 + threadIdx.x;
    if (e >= ne) return;
    int pos = atomicAdd(&cnt[et[e]*n + col[e]], 1);
    ePos[e] = pos;
}

__global__ __launch_bounds__(1024)
void scan_block(const int* __restrict__ cnt, int2* __restrict__ co,
                int* __restrict__ bsum, int n)
{
    __shared__ int s[1024];
    const int t = threadIdx.x;
    const int i = blockIdx.x*1024 + t;
    int v = (i < n) ? cnt[i] : 0;
    s[t] = v;
    __syncthreads();
    #pragma unroll
    for (int d = 1; d < 1024; d <<= 1) {
        int u = (t >= d) ? s[t-d] : 0;
        __syncthreads();
        s[t] += u;
        __syncthreads();
    }
    if (i < n) co[i] = make_int2(v, s[t] - v);
    if (t == 1023) bsum[blockIdx.x] = s[1023];
}

__global__ __launch_bounds__(256)
void scan_bsums(int* __restrict__ bsum, int nb)
{
    __shared__ int s[256];
    const int t = threadIdx.x;
    int v = (t < nb) ? bsum[t] : 0;
    s[t] = v;
    __syncthreads();
    #pragma unroll
    for (int d = 1; d < 256; d <<= 1) {
        int u = (t >= d) ? s[t-d] : 0;
        __syncthreads();
        s[t] += u;
        __syncthreads();
    }
    if (t < nb) bsum[t] = s[t] - v;
}

__global__ __launch_bounds__(256)
void edge_fill(const int* __restrict__ row_idx, const int* __restrict__ col_idx,
               const int* __restrict__ et, const float* __restrict__ ew,
               const int2* __restrict__ co, const int* __restrict__ bsum,
               const int* __restrict__ ePos,
               uint2* __restrict__ ePack, int n, int ne)
{
    int e = blockIdx.x*256 + threadIdx.x;
    if (e >= ne) return;
    int t = et[e], c = col_idx[e], r = row_idx[e];
    int ic = t*n + c;
    int2 qc = co[ic];
    int2 qr = co[t*n + r];
    int idx = qc.y + bsum[ic >> 10] + ePos[e];
    int p = qc.x * qr.x;
    float val = (p > 0) ? ew[e] * rsqrtf((float)p) : 0.f;
    ePack[idx] = make_uint2((unsigned)r, __builtin_bit_cast(unsigned, val));
}

// ---------------------------------------------------------------------------
// CSR gather (bf16 in, bf16 out): one wave per node, lane = 2 feature cols.
// ---------------------------------------------------------------------------
__global__ __launch_bounds__(256)
void hetero_gather(const unsigned short* __restrict__ Gb,
                   const uint2* __restrict__ ePack,
                   const int2* __restrict__ co, const int* __restrict__ bsum,
                   int t0, unsigned short* __restrict__ AGGb, int n)
{
    int node = blockIdx.x*4 + (threadIdx.x >> 6);
    if (node >= n) return;
    const int lane = threadIdx.x & 63;
    const int gi   = t0 + node;
    int2 q = co[gi];
    const int base = q.y + bsum[gi >> 10];
    const int m = q.x;
    float ax = 0.f, ay = 0.f;
    int i = 0;
    for (; i + 3 < m; i += 4) {
        uint2 q0 = ePack[base+i];
        uint2 q1 = ePack[base+i+1];
        uint2 q2 = ePack[base+i+2];
        uint2 q3 = ePack[base+i+3];
        unsigned g0 = *(const unsigned*)&Gb[(size_t)q0.x*128 + lane*2];
        unsigned g1 = *(const unsigned*)&Gb[(size_t)q1.x*128 + lane*2];
        unsigned g2 = *(const unsigned*)&Gb[(size_t)q2.x*128 + lane*2];
        unsigned g3 = *(const unsigned*)&Gb[(size_t)q3.x*128 + lane*2];
        float v0 = __builtin_bit_cast(float, q0.y);
        float v1 = __builtin_bit_cast(float, q1.y);
        float v2 = __builtin_bit_cast(float, q2.y);
        float v3 = __builtin_bit_cast(float, q3.y);
        ax += v0*bf2f(g0 & 0xffff) + v1*bf2f(g1 & 0xffff)
            + v2*bf2f(g2 & 0xffff) + v3*bf2f(g3 & 0xffff);
        ay += v0*bf2f(g0 >> 16)    + v1*bf2f(g1 >> 16)
            + v2*bf2f(g2 >> 16)    + v3*bf2f(g3 >> 16);
    }
    for (; i < m; ++i) {
        uint2 q0 = ePack[base+i];
        unsigned g0 = *(const unsigned*)&Gb[(size_t)q0.x*128 + lane*2];
        float v0 = __builtin_bit_cast(float, q0.y);
        ax += v0*bf2f(g0 & 0xffff);
        ay += v0*bf2f(g0 >> 16);
    }
    unsigned pk = f2bf(ax) | (f2bf(ay) << 16);
    *(unsigned*)&AGGb[(size_t)node*128 + lane*2] = pk;
}

extern "C" void kernel_launch(void* const* d_in, const int* in_sizes, int n_in,
                              void* d_out, int out_size, void* d_ws, size_t ws_size,
                              hipStream_t stream)
{
    const float* x      = (const float*)d_in[0];
    const float* ew     = (const float*)d_in[1];
    const float* t_fc_w = (const float*)d_in[2];
    const float* t_fc_b = (const float*)d_in[3];
    const float* ln0g   = (const float*)d_in[4];
    const float* ln0b   = (const float*)d_in[5];
    const float* wvw    = (const float*)d_in[10];
    const float* wvb    = (const float*)d_in[11];
    const float* ln1g   = (const float*)d_in[12];
    const float* ln1b   = (const float*)d_in[13];
    const float* gfcw   = (const float*)d_in[14];
    const float* gfcb   = (const float*)d_in[15];
    const float* bn0g   = (const float*)d_in[16];
    const float* bn0b   = (const float*)d_in[17];
    const float* bn0m   = (const float*)d_in[18];
    const float* bn0v   = (const float*)d_in[19];
    const float* gw1    = (const float*)d_in[20];
    const float* gb1    = (const float*)d_in[21];
    const float* bn1g   = (const float*)d_in[22];
    const float* bn1b   = (const float*)d_in[23];
    const float* bn1m   = (const float*)d_in[24];
    const float* bn1v   = (const float*)d_in[25];
    const float* gw2    = (const float*)d_in[26];
    const float* gb2    = (const float*)d_in[27];
    const float* bn2g   = (const float*)d_in[28];
    const float* bn2b   = (const float*)d_in[29];
    const float* bn2m   = (const float*)d_in[30];
    const float* bn2v   = (const float*)d_in[31];
    const float* outw   = (const float*)d_in[32];
    const float* outb   = (const float*)d_in[33];
    const int*   ei     = (const int*)d_in[34];
    const int*   et     = (const int*)d_in[35];

    const int N = 100000, E = 800000;
    const size_t NF = (size_t)N*128;
    float* F1 = (float*)d_ws;                         // G1 f32 (resid for g2)
    float* F2 = F1 + NF;                              // G  f32 (resid for g1)
    unsigned short* B1 = (unsigned short*)(F2 + NF);  // AGG0 / AGG1
    unsigned short* B3 = B1 + NF;                     // Gb -> G1b
    unsigned short* B4 = B3 + NF;                     // XTb
    unsigned short* WT = B4 + NF;                     // fragment-layout weights
    unsigned short* wt_tfc = WT;
    unsigned short* wt_wv  = WT + 16384;
    unsigned short* wt_gfc = WT + 2*16384;
    unsigned short* wt_g1  = WT + 3*16384;
    unsigned short* wt_g2  = WT + 4*16384;
    unsigned short* wt_out = WT + 5*16384;
    int*   cnt    = (int*)(WT + 6*16384);             // [2N]
    int2*  co     = (int2*)(cnt + 2*N);               // [2N] {cnt, local off}
    int*   ePos   = (int*)(co + 2*N);                 // [E]
    uint2* ePack  = (uint2*)(ePos + E);               // [E]
    int*   bsum   = (int*)(ePack + E);                // [256]

    dim3 blk(256);
    const int nb64 = (N + 63) / 64;
    const int* row_idx = ei;
    const int* col_idx = ei + E;
    const int nscan = 2*N;
    const int nsb = (nscan + 1023) / 1024;

    // --- CSR build ---
    hipMemsetAsync(cnt, 0, 2*(size_t)N*sizeof(int), stream);
    edge_hist<<<(E + 255)/256, blk, 0, stream>>>(col_idx, et, cnt, ePos, N, E);
    scan_block<<<nsb, 1024, 0, stream>>>(cnt, co, bsum, nscan);
    scan_bsums<<<1, 256, 0, stream>>>(bsum, nsb);
    edge_fill<<<(E + 255)/256, blk, 0, stream>>>(row_idx, col_idx, et, ew,
                                                 co, bsum, ePos, ePack, N, E);

    // --- weights -> bf16 fragment layout ---
    wconv_all<<<48, blk, 0, stream>>>(t_fc_w, wvw, gfcw, gw1, gw2, outw, WT);

    // --- fused front end: XTb, G(f32), Gb ---
    fused_front<<<nb64, blk, 0, stream>>>(x, wt_tfc, wt_wv, wt_gfc,
        t_fc_b, ln0g, ln0b, wvb, ln1g, ln1b,
        gfcb, bn0g, bn0b, bn0m, bn0v, B4, F2, B3, N);

    // --- GNN chain (layer2 GEMM fused with output GEMM) ---
    hetero_gather<<<(N + 3)/4, blk, 0, stream>>>(B3, ePack, co, bsum, 0, B1, N);
    mgemm<<<nb64, blk, 0, stream>>>(B1, wt_g1, gb1, F1, B3, N,
                                    bn1g, bn1b, bn1m, bn1v, F2);
    hetero_gather<<<(N + 3)/4, blk, 0, stream>>>(B3, ePack, co, bsum, N, B1, N);
    mgemm_out<<<nb64, blk, 0, stream>>>(B1, wt_g2, gb2,
        bn2g, bn2b, bn2m, bn2v, F1, B4, wt_out, outb, (float*)d_out, N);
}